// Round 1
// baseline (372.467 us; speedup 1.0000x reference)
//
#include <hip/hip_runtime.h>
#include <hip/hip_bf16.h>

#define NSEQ 2048
#define DM 512
#define BATCH 8
#define GTOT (BATCH * NSEQ)          // 16384
#define INV_T 0.044194173824159216f  // 1/sqrt(512)
#define EPSN 1e-5f

typedef __bf16 bf16_t;
typedef bf16_t bf16x8 __attribute__((ext_vector_type(8)));
typedef float f32x4 __attribute__((ext_vector_type(4)));
typedef unsigned short u16;
typedef unsigned int u32;

__device__ __forceinline__ u16 f2bf(float f) {
    u32 u = __builtin_bit_cast(u32, f);
    u32 r = (u + 0x7FFFu + ((u >> 16) & 1u)) >> 16;
    return (u16)r;
}

// ---------------- kernel 1: f32 -> bf16 conversion of X and W ----------------
__global__ __launch_bounds__(256) void k_convert(
    const float* __restrict__ X, const float* __restrict__ W,
    u16* __restrict__ Kbf, u16* __restrict__ Wbf) {
    const long NK = (long)GTOT * DM / 4;  // 2097152 float4 groups
    const long NW = (long)DM * DM / 4;    // 65536
    long i = (long)blockIdx.x * 256 + threadIdx.x;
    if (i < NK) {
        float4 f = ((const float4*)X)[i];
        ushort4 o;
        o.x = f2bf(f.x); o.y = f2bf(f.y); o.z = f2bf(f.z); o.w = f2bf(f.w);
        ((ushort4*)Kbf)[i] = o;
    } else if (i < NK + NW) {
        long j = i - NK;
        float4 f = ((const float4*)W)[j];
        ushort4 o;
        o.x = f2bf(f.x); o.y = f2bf(f.y); o.z = f2bf(f.z); o.w = f2bf(f.w);
        ((ushort4*)Wbf)[j] = o;
    }
}

// ---------------- kernel 2: vT[e][g] = elu(sum_d W[e][d]*X[g][d] + b[e]) ----
// A = W (register-resident frags), B = X rows staged in LDS. Output stored
// TRANSPOSED (vT) so the flash kernel's PV B-operand staging is natural.
__global__ __launch_bounds__(256, 2) void k_vgemm(
    const u16* __restrict__ Wbf, const u16* __restrict__ Kbf,
    const float* __restrict__ bias, u16* __restrict__ vT) {
    __shared__ __attribute__((aligned(16))) u16 Ks[32 * 520];
    const int tid = threadIdx.x;
    const int wave = tid >> 6, lane = tid & 63, quad = lane >> 4, l15 = lane & 15;
    const int etile = blockIdx.x & 7;   // 8 e-tiles of 64 rows
    const int mblk = blockIdx.x >> 3;   // 64 g-blocks of 256 cols
    const int ebase = etile * 64 + wave * 16;

    // A-frags: 16 rows of W per wave, full K=512 (A[m=l15][k=quad*8+j])
    bf16x8 wf[16];
    {
        const u16* wp = Wbf + (long)(ebase + l15) * DM + quad * 8;
#pragma unroll
        for (int ks = 0; ks < 16; ++ks) wf[ks] = *(const bf16x8*)(wp + ks * 32);
    }
    float bvals[4];
#pragma unroll
    for (int r = 0; r < 4; ++r) bvals[r] = bias[ebase + quad * 4 + r];

    bf16x8 kreg[8];
    // prologue prefetch (mt = 0)
    {
        const int g0 = mblk * 256;
#pragma unroll
        for (int j = 0; j < 8; ++j) {
            int c = tid + 256 * j;
            int row = c >> 6, col = c & 63;
            kreg[j] = *(const bf16x8*)(Kbf + (long)(g0 + row) * DM + col * 8);
        }
    }
    for (int mt = 0; mt < 8; ++mt) {
        const int g0 = mblk * 256 + mt * 32;
        __syncthreads();
#pragma unroll
        for (int j = 0; j < 8; ++j) {
            int c = tid + 256 * j;
            int row = c >> 6, col = c & 63;
            *(bf16x8*)(&Ks[row * 520 + col * 8]) = kreg[j];
        }
        __syncthreads();
        // prefetch next tile while MFMAs run
        {
            int mtn = (mt + 1 < 8) ? mt + 1 : 0;
            const int gn = mblk * 256 + mtn * 32;
#pragma unroll
            for (int j = 0; j < 8; ++j) {
                int c = tid + 256 * j;
                int row = c >> 6, col = c & 63;
                kreg[j] = *(const bf16x8*)(Kbf + (long)(gn + row) * DM + col * 8);
            }
        }
        f32x4 acc[2] = {{0.f, 0.f, 0.f, 0.f}, {0.f, 0.f, 0.f, 0.f}};
#pragma unroll
        for (int ks = 0; ks < 16; ++ks) {
#pragma unroll
            for (int nt = 0; nt < 2; ++nt) {
                bf16x8 kf = *(const bf16x8*)(&Ks[(nt * 16 + l15) * 520 + ks * 32 + quad * 8]);
                acc[nt] = __builtin_amdgcn_mfma_f32_16x16x32_bf16(wf[ks], kf, acc[nt], 0, 0, 0);
            }
        }
        // epilogue: bias + elu, store transposed (C layout: col=l15, row=quad*4+r)
#pragma unroll
        for (int nt = 0; nt < 2; ++nt) {
#pragma unroll
            for (int r = 0; r < 4; ++r) {
                int e = ebase + quad * 4 + r;
                int g = g0 + nt * 16 + l15;
                float x = acc[nt][r] + bvals[r];
                float v = x > 0.f ? x : (__expf(x) - 1.f);
                vT[(long)e * GTOT + g] = f2bf(v);
            }
        }
    }
}

// ---------------- kernel 3: fused masked-similarity attention ----------------
// Per block: 64 rows of one batch; 4 waves x 16 rows. Per m-tile (32 keys):
//   S = Q K^T (MFMA, Q in regs, K in LDS) ; s = S*mask*INV_T ; ss += s^2
//   S->bf16 via wave-private LDS (C->A layout) ; O += S V (V staged transposed)
// Epilogue: O *= 1/max(sqrt(ss), eps).
__global__ __launch_bounds__(256, 1) void k_flash(
    const u16* __restrict__ Kbf, const u16* __restrict__ vT,
    const float* __restrict__ mask, float* __restrict__ Out) {
    __shared__ __attribute__((aligned(16))) u16 KV[512 * 40];   // union: Ks[32][520] / Vs[512][40]
    __shared__ __attribute__((aligned(16))) u16 Sb[4][16 * 40]; // per-wave S buffer
    const int tid = threadIdx.x;
    const int wave = tid >> 6, lane = tid & 63, quad = lane >> 4, l15 = lane & 15;
    const int b = blockIdx.x >> 5;
    const int rblk = blockIdx.x & 31;
    const int r0 = rblk * 64 + wave * 16;  // wave's first row in batch b

    // Q frags: A[m=l15][k=quad*8+j], 16 k-steps covering D=512
    bf16x8 qf[16];
    {
        const u16* qp = Kbf + (long)(b * NSEQ + r0 + l15) * DM + quad * 8;
#pragma unroll
        for (int ks = 0; ks < 16; ++ks) qf[ks] = *(const bf16x8*)(qp + ks * 32);
    }
    f32x4 oacc[32];
#pragma unroll
    for (int i = 0; i < 32; ++i) oacc[i] = (f32x4){0.f, 0.f, 0.f, 0.f};
    float ss[4] = {0.f, 0.f, 0.f, 0.f};

    const float* mrow = mask + (long)(b * NSEQ + r0 + quad * 4) * NSEQ;
    const u16* kbase = Kbf + (long)b * NSEQ * DM;
    const u16* vbase = vT + (long)b * NSEQ;

    bf16x8 kreg[8];
    float mv[8];
    // prologue prefetch (mt = 0)
#pragma unroll
    for (int j = 0; j < 8; ++j) {
        int c = tid + 256 * j;
        int row = c >> 6, col = c & 63;
        kreg[j] = *(const bf16x8*)(kbase + (long)row * DM + col * 8);
    }
#pragma unroll
    for (int q = 0; q < 8; ++q) {
        int nt = q >> 2, r = q & 3;
        mv[q] = mrow[(long)r * NSEQ + nt * 16 + l15];
    }

    for (int mt = 0; mt < 64; ++mt) {
        const int m0 = mt * 32;
        __syncthreads();  // (1) prior PV reads of KV complete
#pragma unroll
        for (int j = 0; j < 8; ++j) {
            int c = tid + 256 * j;
            int row = c >> 6, col = c & 63;
            *(bf16x8*)(&KV[row * 520 + col * 8]) = kreg[j];
        }
        __syncthreads();  // (2) Ks visible
        // prefetch this tile's V (regs only; LDS still holds Ks)
        bf16x8 vreg[8];
#pragma unroll
        for (int dh = 0; dh < 2; ++dh) {
            int d = tid + dh * 256;
            const u16* vp = vbase + (long)d * GTOT + m0;
#pragma unroll
            for (int j = 0; j < 4; ++j) vreg[dh * 4 + j] = *(const bf16x8*)(vp + j * 8);
        }
        // S = Q K^T
        f32x4 sacc[2] = {{0.f, 0.f, 0.f, 0.f}, {0.f, 0.f, 0.f, 0.f}};
#pragma unroll
        for (int ks = 0; ks < 16; ++ks) {
#pragma unroll
            for (int nt = 0; nt < 2; ++nt) {
                bf16x8 kf = *(const bf16x8*)(&KV[(nt * 16 + l15) * 520 + ks * 32 + quad * 8]);
                sacc[nt] = __builtin_amdgcn_mfma_f32_16x16x32_bf16(qf[ks], kf, sacc[nt], 0, 0, 0);
            }
        }
        // mask * INV_T, sum-of-squares, write S (bf16) to wave-private LDS
#pragma unroll
        for (int nt = 0; nt < 2; ++nt) {
#pragma unroll
            for (int r = 0; r < 4; ++r) {
                float s = sacc[nt][r] * mv[nt * 4 + r] * INV_T;
                ss[r] += s * s;
                Sb[wave][(quad * 4 + r) * 40 + nt * 16 + l15] = f2bf(s);
            }
        }
        __syncthreads();  // (3) all waves done reading Ks
#pragma unroll
        for (int dh = 0; dh < 2; ++dh) {
            int d = tid + dh * 256;
#pragma unroll
            for (int j = 0; j < 4; ++j) *(bf16x8*)(&KV[d * 40 + j * 8]) = vreg[dh * 4 + j];
        }
        // prefetch next iteration's K tile + mask (overlaps PV MFMAs)
        {
            int mtn = (mt + 1 < 64) ? mt + 1 : 0;
            const int mn = mtn * 32;
#pragma unroll
            for (int j = 0; j < 8; ++j) {
                int c = tid + 256 * j;
                int row = c >> 6, col = c & 63;
                kreg[j] = *(const bf16x8*)(kbase + (long)(mn + row) * DM + col * 8);
            }
#pragma unroll
            for (int q = 0; q < 8; ++q) {
                int nt = q >> 2, r = q & 3;
                mv[q] = mrow[(long)r * NSEQ + mn + nt * 16 + l15];
            }
        }
        __syncthreads();  // (4) Vs visible
        // O += S V   (A from Sb: A[m=l15][k=quad*8+j]; B from Vs[d][m])
        bf16x8 af = *(const bf16x8*)(&Sb[wave][l15 * 40 + quad * 8]);
#pragma unroll
        for (int nt = 0; nt < 32; ++nt) {
            bf16x8 vf = *(const bf16x8*)(&KV[(nt * 16 + l15) * 40 + quad * 8]);
            oacc[nt] = __builtin_amdgcn_mfma_f32_16x16x32_bf16(af, vf, oacc[nt], 0, 0, 0);
        }
    }
    // reduce ss over the 16 lanes of each quad (cols of each row)
#pragma unroll
    for (int r = 0; r < 4; ++r) {
        float v = ss[r];
        v += __shfl_xor(v, 1, 16);
        v += __shfl_xor(v, 2, 16);
        v += __shfl_xor(v, 4, 16);
        v += __shfl_xor(v, 8, 16);
        ss[r] = 1.f / fmaxf(sqrtf(v), EPSN);
    }
    float* op = Out + (long)(b * NSEQ + r0 + quad * 4) * DM + l15;
#pragma unroll
    for (int nt = 0; nt < 32; ++nt) {
#pragma unroll
        for (int r = 0; r < 4; ++r) op[(long)r * DM + nt * 16] = oacc[nt][r] * ss[r];
    }
}

extern "C" void kernel_launch(void* const* d_in, const int* in_sizes, int n_in,
                              void* d_out, int out_size, void* d_ws, size_t ws_size,
                              hipStream_t stream) {
    const float* X = (const float*)d_in[0];     // output [8,2048,512]
    const float* mask = (const float*)d_in[1];  // [8,2048,2048]
    const float* W = (const float*)d_in[2];     // [512,512]
    const float* bias = (const float*)d_in[3];  // [512]
    float* out = (float*)d_out;

    char* ws = (char*)d_ws;
    u16* Kbf = (u16*)ws;                          // 16 MiB  (X as bf16)
    u16* Wbf = (u16*)(ws + 16777216);             // 512 KiB (W as bf16)
    u16* vT = (u16*)(ws + 16777216 + 524288);     // 16 MiB  (v transposed, bf16)

    k_convert<<<8448, 256, 0, stream>>>(X, W, Kbf, Wbf);
    k_vgemm<<<512, 256, 0, stream>>>(Wbf, Kbf, bias, vT);
    k_flash<<<256, 256, 0, stream>>>(Kbf, vT, mask, out);
}

// Round 2
// 360.278 us; speedup vs baseline: 1.0338x; 1.0338x over previous
//
#include <hip/hip_runtime.h>
#include <hip/hip_bf16.h>

#define NSEQ 2048
#define DM 512
#define BATCH 8
#define GTOT (BATCH * NSEQ)          // 16384
#define INV_T 0.044194173824159216f  // 1/sqrt(512)
#define EPSN 1e-5f

typedef __bf16 bf16_t;
typedef bf16_t bf16x8 __attribute__((ext_vector_type(8)));
typedef float f32x4 __attribute__((ext_vector_type(4)));
typedef float f32x16 __attribute__((ext_vector_type(16)));
typedef unsigned short u16;
typedef unsigned int u32;

__device__ __forceinline__ u16 f2bf(float f) {
    u32 u = __builtin_bit_cast(u32, f);
    u32 r = (u + 0x7FFFu + ((u >> 16) & 1u)) >> 16;
    return (u16)r;
}

// ---------------- kernel 1: f32 -> bf16 conversion of X and W ----------------
__global__ __launch_bounds__(256) void k_convert(
    const float* __restrict__ X, const float* __restrict__ W,
    u16* __restrict__ Kbf, u16* __restrict__ Wbf) {
    const long NK = (long)GTOT * DM / 4;
    const long NW = (long)DM * DM / 4;
    long i = (long)blockIdx.x * 256 + threadIdx.x;
    if (i < NK) {
        float4 f = ((const float4*)X)[i];
        ushort4 o;
        o.x = f2bf(f.x); o.y = f2bf(f.y); o.z = f2bf(f.z); o.w = f2bf(f.w);
        ((ushort4*)Kbf)[i] = o;
    } else if (i < NK + NW) {
        long j = i - NK;
        float4 f = ((const float4*)W)[j];
        ushort4 o;
        o.x = f2bf(f.x); o.y = f2bf(f.y); o.z = f2bf(f.z); o.w = f2bf(f.w);
        ((ushort4*)Wbf)[j] = o;
    }
}

// ---------------- kernel 2: vT[e][g] = elu(sum_d W[e][d]*X[g][d] + b[e]) ----
__global__ __launch_bounds__(256, 2) void k_vgemm(
    const u16* __restrict__ Wbf, const u16* __restrict__ Kbf,
    const float* __restrict__ bias, u16* __restrict__ vT) {
    __shared__ __attribute__((aligned(16))) u16 Ks[32 * 520];
    const int tid = threadIdx.x;
    const int wave = tid >> 6, lane = tid & 63, quad = lane >> 4, l15 = lane & 15;
    const int etile = blockIdx.x & 7;
    const int mblk = blockIdx.x >> 3;
    const int ebase = etile * 64 + wave * 16;

    bf16x8 wf[16];
    {
        const u16* wp = Wbf + (long)(ebase + l15) * DM + quad * 8;
#pragma unroll
        for (int ks = 0; ks < 16; ++ks) wf[ks] = *(const bf16x8*)(wp + ks * 32);
    }
    float bvals[4];
#pragma unroll
    for (int r = 0; r < 4; ++r) bvals[r] = bias[ebase + quad * 4 + r];

    bf16x8 kreg[8];
    {
        const int g0 = mblk * 256;
#pragma unroll
        for (int j = 0; j < 8; ++j) {
            int c = tid + 256 * j;
            int row = c >> 6, col = c & 63;
            kreg[j] = *(const bf16x8*)(Kbf + (long)(g0 + row) * DM + col * 8);
        }
    }
    for (int mt = 0; mt < 8; ++mt) {
        const int g0 = mblk * 256 + mt * 32;
        __syncthreads();
#pragma unroll
        for (int j = 0; j < 8; ++j) {
            int c = tid + 256 * j;
            int row = c >> 6, col = c & 63;
            *(bf16x8*)(&Ks[row * 520 + col * 8]) = kreg[j];
        }
        __syncthreads();
        {
            int mtn = (mt + 1 < 8) ? mt + 1 : 0;
            const int gn = mblk * 256 + mtn * 32;
#pragma unroll
            for (int j = 0; j < 8; ++j) {
                int c = tid + 256 * j;
                int row = c >> 6, col = c & 63;
                kreg[j] = *(const bf16x8*)(Kbf + (long)(gn + row) * DM + col * 8);
            }
        }
        f32x4 acc[2] = {{0.f, 0.f, 0.f, 0.f}, {0.f, 0.f, 0.f, 0.f}};
#pragma unroll
        for (int ks = 0; ks < 16; ++ks) {
#pragma unroll
            for (int nt = 0; nt < 2; ++nt) {
                bf16x8 kf = *(const bf16x8*)(&Ks[(nt * 16 + l15) * 520 + ks * 32 + quad * 8]);
                acc[nt] = __builtin_amdgcn_mfma_f32_16x16x32_bf16(wf[ks], kf, acc[nt], 0, 0, 0);
            }
        }
#pragma unroll
        for (int nt = 0; nt < 2; ++nt) {
#pragma unroll
            for (int r = 0; r < 4; ++r) {
                int e = ebase + quad * 4 + r;
                int g = g0 + nt * 16 + l15;
                float x = acc[nt][r] + bvals[r];
                float v = x > 0.f ? x : (__expf(x) - 1.f);
                vT[(long)e * GTOT + g] = f2bf(v);
            }
        }
    }
}

// ---------------- kernel 3: fused masked-similarity attention ----------------
// 512 threads = 8 waves, 64 rows/block, m-tile = 64 keys, 32 iterations.
// S-phase: wave (rg=w>>1, kh=w&1): S[rg*16..+15][kh*32..+31] via 16x16x32, Q in regs.
// PV-phase: wave (rgp=w>>2, dq=w&3): O[rgp*32..+31][dq*128..+127] via 32x32x16.
// ss (row sum of squares) accumulated per kh-half, cross-wave reduced at end.
__global__ __launch_bounds__(512, 2) void k_flash(
    const u16* __restrict__ Kbf, const u16* __restrict__ vT,
    const float* __restrict__ mask, float* __restrict__ Out) {
    extern __shared__ char smem[];
    u16* Ks = (u16*)smem;                          // 64 x 520  = 66560 B
    u16* Vs = (u16*)(smem + 66560);                // 512 x 72  = 73728 B
    u16* Ss = (u16*)(smem + 66560 + 73728);        // 64 x 72   =  9216 B
    float* ssred = (float*)(smem + 149504);        // 128 floats =  512 B

    const int tid = threadIdx.x;
    const int wave = tid >> 6, lane = tid & 63;
    const int quad = lane >> 4, l15 = lane & 15;
    const int l31 = lane & 31, lh = lane >> 5;
    const int rg = wave >> 1, kh = wave & 1;   // S-phase mapping
    const int rgp = wave >> 2, dq = wave & 3;  // PV mapping
    const int b = blockIdx.x >> 5;
    const int rblk = blockIdx.x & 31;
    const int row0 = rblk * 64;

    // Q frags: rows rg*16 + l15, A[m=l15][k=quad*8+j]
    bf16x8 qf[16];
    {
        const u16* qp = Kbf + (long)(b * NSEQ + row0 + rg * 16 + l15) * DM + quad * 8;
#pragma unroll
        for (int ks = 0; ks < 16; ++ks) qf[ks] = *(const bf16x8*)(qp + ks * 32);
    }
    f32x16 oacc[4];
#pragma unroll
    for (int i = 0; i < 4; ++i)
#pragma unroll
        for (int j = 0; j < 16; ++j) oacc[i][j] = 0.f;
    float ss[4] = {0.f, 0.f, 0.f, 0.f};

    const u16* kbase = Kbf + (long)b * NSEQ * DM;
    const u16* vbase = vT + (long)b * NSEQ;  // column offset in g-dim
    const float* mrow = mask + (long)(b * NSEQ + row0 + rg * 16 + quad * 4) * NSEQ + kh * 32;

    bf16x8 kreg[8], vreg[8];
    float mv[8];
    // prologue prefetch (mt = 0)
#pragma unroll
    for (int j = 0; j < 8; ++j) {
        int c = tid + 512 * j;
        kreg[j] = *(const bf16x8*)(kbase + (long)(c >> 6) * DM + (c & 63) * 8);
    }
#pragma unroll
    for (int j = 0; j < 8; ++j) {
        int c = tid + 512 * j;
        vreg[j] = *(const bf16x8*)(vbase + (long)(c >> 3) * GTOT + (c & 7) * 8);
    }
#pragma unroll
    for (int q = 0; q < 8; ++q) {
        int nt = q >> 2, r = q & 3;
        mv[q] = mrow[(long)r * NSEQ + nt * 16 + l15];
    }

    for (int mt = 0; mt < 32; ++mt) {
        __syncthreads();  // B1: prior PV reads of Vs/Ss and S reads of Ks done
#pragma unroll
        for (int j = 0; j < 8; ++j) {
            int c = tid + 512 * j;
            *(bf16x8*)(&Ks[(c >> 6) * 520 + (c & 63) * 8]) = kreg[j];
        }
#pragma unroll
        for (int j = 0; j < 8; ++j) {
            int c = tid + 512 * j;
            *(bf16x8*)(&Vs[(c >> 3) * 72 + (c & 7) * 8]) = vreg[j];
        }
        __syncthreads();  // B2: Ks/Vs visible
        // S = Q K^T over this wave's 32-key half
        f32x4 sacc[2] = {{0.f, 0.f, 0.f, 0.f}, {0.f, 0.f, 0.f, 0.f}};
#pragma unroll
        for (int ks = 0; ks < 16; ++ks) {
#pragma unroll
            for (int nt = 0; nt < 2; ++nt) {
                bf16x8 kf = *(const bf16x8*)(&Ks[(kh * 32 + nt * 16 + l15) * 520 + ks * 32 + quad * 8]);
                sacc[nt] = __builtin_amdgcn_mfma_f32_16x16x32_bf16(qf[ks], kf, sacc[nt], 0, 0, 0);
            }
        }
        // mask * INV_T, sum-of-squares, S -> LDS (bf16)
#pragma unroll
        for (int nt = 0; nt < 2; ++nt) {
#pragma unroll
            for (int r = 0; r < 4; ++r) {
                float s = sacc[nt][r] * mv[nt * 4 + r] * INV_T;
                ss[r] += s * s;
                Ss[(rg * 16 + quad * 4 + r) * 72 + kh * 32 + nt * 16 + l15] = f2bf(s);
            }
        }
        __syncthreads();  // B3: Ss visible
        // prefetch next tile (overlaps PV MFMAs; drained at next B1)
        {
            int mtn = (mt + 1) & 31;
            const int mn = mtn * 64;
#pragma unroll
            for (int j = 0; j < 8; ++j) {
                int c = tid + 512 * j;
                kreg[j] = *(const bf16x8*)(kbase + (long)(mn + (c >> 6)) * DM + (c & 63) * 8);
            }
#pragma unroll
            for (int j = 0; j < 8; ++j) {
                int c = tid + 512 * j;
                vreg[j] = *(const bf16x8*)(vbase + (long)(c >> 3) * GTOT + mn + (c & 7) * 8);
            }
#pragma unroll
            for (int q = 0; q < 8; ++q) {
                int nt = q >> 2, r = q & 3;
                mv[q] = mrow[(long)r * NSEQ + mn + nt * 16 + l15];
            }
        }
        // PV: O[rgp*32..][dq*128..] += S V  (32x32x16; A m=l31,k=lh*8+j; B n=l31,k=lh*8+j)
#pragma unroll
        for (int kk = 0; kk < 4; ++kk) {
            bf16x8 af = *(const bf16x8*)(&Ss[(rgp * 32 + l31) * 72 + kk * 16 + lh * 8]);
#pragma unroll
            for (int dt = 0; dt < 4; ++dt) {
                bf16x8 vf = *(const bf16x8*)(&Vs[(dq * 128 + dt * 32 + l31) * 72 + kk * 16 + lh * 8]);
                oacc[dt] = __builtin_amdgcn_mfma_f32_32x32x16_bf16(af, vf, oacc[dt], 0, 0, 0);
            }
        }
    }
    // reduce ss across the 16 lanes of each quad (partial over kh half)
#pragma unroll
    for (int r = 0; r < 4; ++r) {
        float v = ss[r];
        v += __shfl_xor(v, 1, 16);
        v += __shfl_xor(v, 2, 16);
        v += __shfl_xor(v, 4, 16);
        v += __shfl_xor(v, 8, 16);
        if (l15 == 0) ssred[wave * 16 + quad * 4 + r] = v;  // [rg][kh][16]
    }
    __syncthreads();
    // epilogue: combine kh halves, normalize, store (C32 layout: col=l31, row=(reg&3)+8*(reg>>2)+4*lh)
#pragma unroll
    for (int reg = 0; reg < 16; ++reg) {
        int rowoff = (reg & 3) + 8 * (reg >> 2) + 4 * lh;
        int R = rgp * 32 + rowoff;
        float tot = ssred[(R >> 4) * 32 + (R & 15)] + ssred[(R >> 4) * 32 + 16 + (R & 15)];
        float sc = 1.f / fmaxf(sqrtf(tot), EPSN);
        float* op = Out + (long)(b * NSEQ + row0 + R) * DM + dq * 128 + l31;
#pragma unroll
        for (int dt = 0; dt < 4; ++dt) op[dt * 32] = oacc[dt][reg] * sc;
    }
}

extern "C" void kernel_launch(void* const* d_in, const int* in_sizes, int n_in,
                              void* d_out, int out_size, void* d_ws, size_t ws_size,
                              hipStream_t stream) {
    const float* X = (const float*)d_in[0];
    const float* mask = (const float*)d_in[1];
    const float* W = (const float*)d_in[2];
    const float* bias = (const float*)d_in[3];
    float* out = (float*)d_out;

    char* ws = (char*)d_ws;
    u16* Kbf = (u16*)ws;                          // 16 MiB
    u16* Wbf = (u16*)(ws + 16777216);             // 512 KiB
    u16* vT = (u16*)(ws + 16777216 + 524288);     // 16 MiB

    k_convert<<<8448, 256, 0, stream>>>(X, W, Kbf, Wbf);
    k_vgemm<<<512, 256, 0, stream>>>(Wbf, Kbf, bias, vT);
    k_flash<<<256, 512, 150016, stream>>>(Kbf, vT, mask, out);
}

// Round 3
// 354.434 us; speedup vs baseline: 1.0509x; 1.0165x over previous
//
#include <hip/hip_runtime.h>
#include <hip/hip_bf16.h>

#define NSEQ 2048
#define DM 512
#define BATCH 8
#define GTOT (BATCH * NSEQ)          // 16384
#define INV_T 0.044194173824159216f  // 1/sqrt(512)
#define EPSN 1e-5f

typedef __bf16 bf16_t;
typedef bf16_t bf16x8 __attribute__((ext_vector_type(8)));
typedef float f32x16 __attribute__((ext_vector_type(16)));
typedef unsigned short u16;
typedef unsigned int u32;

__device__ __forceinline__ u16 f2bf(float f) {
    u32 u = __builtin_bit_cast(u32, f);
    u32 r = (u + 0x7FFFu + ((u >> 16) & 1u)) >> 16;
    return (u16)r;
}

// async global->LDS DMA, 16 B per lane. LDS dest = wave-uniform base + lane*16.
__device__ __forceinline__ void async16(const u16* g, u16* l) {
    __builtin_amdgcn_global_load_lds(
        (const __attribute__((address_space(1))) u32*)g,
        (__attribute__((address_space(3))) u32*)l, 16, 0, 0);
}

// LDS tile: 128 rows x 32 k-elems (64 B rows), 16-B chunks XOR-swizzled by ((row>>1)&3).
__device__ __forceinline__ bf16x8 fragld(const u16* t, int row, int kc) {
    return *(const bf16x8*)(t + row * 32 + ((kc ^ ((row >> 1) & 3)) << 3));
}

#define MFMA32(a, b, c) __builtin_amdgcn_mfma_f32_32x32x16_bf16(a, b, c, 0, 0, 0)
#define ROWOFF(reg, lh) (((reg) & 3) + 8 * ((reg) >> 2) + 4 * (lh))

// Staging helper macro: 4 issues per thread (2 A + 2 B), swizzled chunk on global side.
#define STAGE(Ag, ldA, Bg, ldB, k0)                                              \
    do {                                                                         \
        async16((Ag) + (long)rA0 * (ldA) + (k0) + kcg * 8, Ab + u0 * 512 + lane * 8);        \
        async16((Ag) + (long)(rA0 + 16) * (ldA) + (k0) + kcg * 8, Ab + (u0 + 1) * 512 + lane * 8); \
        async16((Bg) + (long)rA0 * (ldB) + (k0) + kcg * 8, Bb + u0 * 512 + lane * 8);        \
        async16((Bg) + (long)(rA0 + 16) * (ldB) + (k0) + kcg * 8, Bb + (u0 + 1) * 512 + lane * 8); \
    } while (0)

// ---------------- kernel 1: f32 -> bf16 of X and W; zero ssbuf ----------------
__global__ __launch_bounds__(256) void k_convert(
    const float* __restrict__ X, const float* __restrict__ W,
    u16* __restrict__ Kbf, u16* __restrict__ Wbf, float* __restrict__ ssbuf) {
    const long NK = (long)GTOT * DM / 4;  // 2097152
    const long NW = (long)DM * DM / 4;    // 65536
    const long NS = GTOT / 4;             // 4096 (ssbuf float4 groups)
    long i = (long)blockIdx.x * 256 + threadIdx.x;
    if (i < NK) {
        float4 f = ((const float4*)X)[i];
        ushort4 o;
        o.x = f2bf(f.x); o.y = f2bf(f.y); o.z = f2bf(f.z); o.w = f2bf(f.w);
        ((ushort4*)Kbf)[i] = o;
    } else if (i < NK + NW) {
        long j = i - NK;
        float4 f = ((const float4*)W)[j];
        ushort4 o;
        o.x = f2bf(f.x); o.y = f2bf(f.y); o.z = f2bf(f.z); o.w = f2bf(f.w);
        ((ushort4*)Wbf)[j] = o;
    } else if (i < NK + NW + NS) {
        ((float4*)ssbuf)[i - NK - NW] = (float4){0.f, 0.f, 0.f, 0.f};
    }
}

// ------------- kernel 2: vT[e][g] = elu(W X^T + b), m97-style GEMM -------------
// M = 512 (e, A=W), N = 16384 (g, B^T=X), K = 512.
__global__ __launch_bounds__(256, 4) void k_vgemm(
    const u16* __restrict__ Wbf, const u16* __restrict__ Kbf,
    const float* __restrict__ bias, u16* __restrict__ vT) {
    __shared__ __attribute__((aligned(16))) u16 Ab[4096], Bb[4096];
    const int tid = threadIdx.x, wave = tid >> 6, lane = tid & 63;
    const int l31 = lane & 31, lh = lane >> 5;
    const int wy = wave >> 1, wx = wave & 1;
    const int M0 = blockIdx.y * 128, N0 = blockIdx.x * 128;
    const u16* Ag = Wbf + (long)M0 * DM;
    const u16* Bg = Kbf + (long)N0 * DM;

    const int u0 = wave * 2;
    const int rA0 = u0 * 16 + (lane >> 2);
    const int kcg = (lane & 3) ^ ((lane >> 3) & 3);

    f32x16 acc[2][2];
#pragma unroll
    for (int i = 0; i < 2; ++i)
#pragma unroll
        for (int j = 0; j < 2; ++j)
#pragma unroll
            for (int e = 0; e < 16; ++e) acc[i][j][e] = 0.f;

    for (int kt = 0; kt < 16; ++kt) {
        const int k0 = kt * 32;
        __syncthreads();
        STAGE(Ag, DM, Bg, DM, k0);
        __syncthreads();
#pragma unroll
        for (int ks = 0; ks < 2; ++ks) {
            int kc = ks * 2 + lh;
            bf16x8 a0 = fragld(Ab, wy * 64 + l31, kc);
            bf16x8 a1 = fragld(Ab, wy * 64 + 32 + l31, kc);
            bf16x8 b0 = fragld(Bb, wx * 64 + l31, kc);
            bf16x8 b1 = fragld(Bb, wx * 64 + 32 + l31, kc);
            acc[0][0] = MFMA32(a0, b0, acc[0][0]);
            acc[0][1] = MFMA32(a0, b1, acc[0][1]);
            acc[1][0] = MFMA32(a1, b0, acc[1][0]);
            acc[1][1] = MFMA32(a1, b1, acc[1][1]);
        }
    }
#pragma unroll
    for (int mi = 0; mi < 2; ++mi) {
#pragma unroll
        for (int reg = 0; reg < 16; ++reg) {
            int e = M0 + wy * 64 + mi * 32 + ROWOFF(reg, lh);
            float bv = bias[e];
#pragma unroll
            for (int ni = 0; ni < 2; ++ni) {
                int g = N0 + wx * 64 + ni * 32 + l31;
                float x = acc[mi][ni][reg] + bv;
                float v = x > 0.f ? x : (__expf(x) - 1.f);
                vT[(long)e * GTOT + g] = f2bf(v);
            }
        }
    }
}

// --- kernel 3: S = mask .* (X X^T) * INV_T (bf16) + row sum-of-squares atomics ---
// Per batch: M = N = 2048, K = 512. A rows = queries, B^T rows = keys (both Kbf).
__global__ __launch_bounds__(256, 4) void k_sgemm(
    const u16* __restrict__ Kbf, const float* __restrict__ mask,
    u16* __restrict__ Sbuf, float* __restrict__ ssbuf) {
    __shared__ __attribute__((aligned(16))) u16 Ab[4096], Bb[4096];
    const int tid = threadIdx.x, wave = tid >> 6, lane = tid & 63;
    const int l31 = lane & 31, lh = lane >> 5;
    const int wy = wave >> 1, wx = wave & 1;
    const int b = blockIdx.z;
    const int M0 = blockIdx.y * 128, N0 = blockIdx.x * 128;
    const u16* Ag = Kbf + (long)(b * NSEQ + M0) * DM;
    const u16* Bg = Kbf + (long)(b * NSEQ + N0) * DM;

    const int u0 = wave * 2;
    const int rA0 = u0 * 16 + (lane >> 2);
    const int kcg = (lane & 3) ^ ((lane >> 3) & 3);

    f32x16 acc[2][2];
#pragma unroll
    for (int i = 0; i < 2; ++i)
#pragma unroll
        for (int j = 0; j < 2; ++j)
#pragma unroll
            for (int e = 0; e < 16; ++e) acc[i][j][e] = 0.f;

    for (int kt = 0; kt < 16; ++kt) {
        const int k0 = kt * 32;
        __syncthreads();
        STAGE(Ag, DM, Bg, DM, k0);
        __syncthreads();
#pragma unroll
        for (int ks = 0; ks < 2; ++ks) {
            int kc = ks * 2 + lh;
            bf16x8 a0 = fragld(Ab, wy * 64 + l31, kc);
            bf16x8 a1 = fragld(Ab, wy * 64 + 32 + l31, kc);
            bf16x8 b0 = fragld(Bb, wx * 64 + l31, kc);
            bf16x8 b1 = fragld(Bb, wx * 64 + 32 + l31, kc);
            acc[0][0] = MFMA32(a0, b0, acc[0][0]);
            acc[0][1] = MFMA32(a0, b1, acc[0][1]);
            acc[1][0] = MFMA32(a1, b0, acc[1][0]);
            acc[1][1] = MFMA32(a1, b1, acc[1][1]);
        }
    }
    // epilogue: mask multiply, bf16 store, per-row sum-of-squares -> atomicAdd
#pragma unroll
    for (int mi = 0; mi < 2; ++mi) {
#pragma unroll
        for (int reg = 0; reg < 16; ++reg) {
            long rg = (long)b * NSEQ + M0 + wy * 64 + mi * 32 + ROWOFF(reg, lh);
            float v = 0.f;
#pragma unroll
            for (int ni = 0; ni < 2; ++ni) {
                int cg = N0 + wx * 64 + ni * 32 + l31;
                float s = acc[mi][ni][reg] * INV_T * mask[rg * NSEQ + cg];
                v += s * s;
                Sbuf[rg * NSEQ + cg] = f2bf(s);
            }
            v += __shfl_xor(v, 1, 32);
            v += __shfl_xor(v, 2, 32);
            v += __shfl_xor(v, 4, 32);
            v += __shfl_xor(v, 8, 32);
            v += __shfl_xor(v, 16, 32);
            if (l31 == 0) atomicAdd(&ssbuf[rg], v);
        }
    }
}

// -------- kernel 4: O = diag(1/max(||S_row||,eps)) * (S V), m97-style ---------
// Per batch: M = 2048, N = 512 (d), K = 2048. A = S (bf16), B^T = vT.
__global__ __launch_bounds__(256, 4) void k_pv(
    const u16* __restrict__ Sbuf, const u16* __restrict__ vT,
    const float* __restrict__ ssbuf, float* __restrict__ Out) {
    __shared__ __attribute__((aligned(16))) u16 Ab[4096], Bb[4096];
    __shared__ float sc[128];
    const int tid = threadIdx.x, wave = tid >> 6, lane = tid & 63;
    const int l31 = lane & 31, lh = lane >> 5;
    const int wy = wave >> 1, wx = wave & 1;
    const int b = blockIdx.z;
    const int M0 = blockIdx.y * 128, N0 = blockIdx.x * 128;
    const u16* Ag = Sbuf + (long)(b * NSEQ + M0) * NSEQ;
    const u16* Bg = vT + (long)N0 * GTOT + b * NSEQ;

    if (tid < 128) {
        float v = ssbuf[b * NSEQ + M0 + tid];
        sc[tid] = 1.f / fmaxf(sqrtf(v), EPSN);
    }

    const int u0 = wave * 2;
    const int rA0 = u0 * 16 + (lane >> 2);
    const int kcg = (lane & 3) ^ ((lane >> 3) & 3);

    f32x16 acc[2][2];
#pragma unroll
    for (int i = 0; i < 2; ++i)
#pragma unroll
        for (int j = 0; j < 2; ++j)
#pragma unroll
            for (int e = 0; e < 16; ++e) acc[i][j][e] = 0.f;

    for (int kt = 0; kt < 64; ++kt) {
        const int k0 = kt * 32;
        __syncthreads();
        STAGE(Ag, NSEQ, Bg, GTOT, k0);
        __syncthreads();
#pragma unroll
        for (int ks = 0; ks < 2; ++ks) {
            int kc = ks * 2 + lh;
            bf16x8 a0 = fragld(Ab, wy * 64 + l31, kc);
            bf16x8 a1 = fragld(Ab, wy * 64 + 32 + l31, kc);
            bf16x8 b0 = fragld(Bb, wx * 64 + l31, kc);
            bf16x8 b1 = fragld(Bb, wx * 64 + 32 + l31, kc);
            acc[0][0] = MFMA32(a0, b0, acc[0][0]);
            acc[0][1] = MFMA32(a0, b1, acc[0][1]);
            acc[1][0] = MFMA32(a1, b0, acc[1][0]);
            acc[1][1] = MFMA32(a1, b1, acc[1][1]);
        }
    }
#pragma unroll
    for (int mi = 0; mi < 2; ++mi) {
#pragma unroll
        for (int reg = 0; reg < 16; ++reg) {
            int rl = wy * 64 + mi * 32 + ROWOFF(reg, lh);
            float s = sc[rl];
            float* op = Out + ((long)b * NSEQ + M0 + rl) * DM;
#pragma unroll
            for (int ni = 0; ni < 2; ++ni) {
                int d = N0 + wx * 64 + ni * 32 + l31;
                op[d] = acc[mi][ni][reg] * s;
            }
        }
    }
}

extern "C" void kernel_launch(void* const* d_in, const int* in_sizes, int n_in,
                              void* d_out, int out_size, void* d_ws, size_t ws_size,
                              hipStream_t stream) {
    const float* X = (const float*)d_in[0];
    const float* mask = (const float*)d_in[1];
    const float* W = (const float*)d_in[2];
    const float* bias = (const float*)d_in[3];
    float* out = (float*)d_out;

    char* ws = (char*)d_ws;
    u16* Kbf = (u16*)ws;                           // 16 MiB
    u16* Wbf = (u16*)(ws + 16777216);              // 512 KiB
    u16* vT = (u16*)(ws + 17301504);               // 16 MiB
    u16* Sbuf = (u16*)(ws + 34078720);             // 64 MiB
    float* ssbuf = (float*)(ws + 101187584);       // 64 KiB   (total ~96.6 MiB)

    k_convert<<<8464, 256, 0, stream>>>(X, W, Kbf, Wbf, ssbuf);
    k_vgemm<<<dim3(128, 4), 256, 0, stream>>>(Wbf, Kbf, bias, vT);
    k_sgemm<<<dim3(16, 16, 8), 256, 0, stream>>>(Kbf, mask, Sbuf, ssbuf);
    k_pv<<<dim3(4, 16, 8), 256, 0, stream>>>(Sbuf, vT, ssbuf, out);
}